// Round 6
// baseline (87.248 us; speedup 1.0000x reference)
//
#include <hip/hip_runtime.h>

#define N_SLOTS 65536
#define DIM 128
#define B_SZ 4096
#define K_TOP 8
#define UPDATE_RATE 0.1f
#define MOMENTUM 0.9f
#define GATE_THRESH 0.01f

typedef float f32x4 __attribute__((ext_vector_type(4)));

// ---------------------------------------------------------------------------
// MEASUREMENT PROBE (R6 only): pure-read bandwidth over all four input
// buffers (134 MB). 2048 blocks x 256 threads; each thread issues 16
// independent f32x4 loads (4 per buffer, lane-contiguous), reduces, and
// writes one float to ws (DCE guard, 2 MB total writes = 1.5% overhead).
// Purpose: measure achievable READ bandwidth in-harness, and via its
// FETCH_SIZE whether the inputs are L3-resident in steady state.
// ---------------------------------------------------------------------------
__global__ void __launch_bounds__(256) mw_read_probe(
        const f32x4* __restrict__ mk,
        const f32x4* __restrict__ km,
        const f32x4* __restrict__ mv,
        const f32x4* __restrict__ vm,
        float* __restrict__ probe_out) {
    int base = blockIdx.x * 1024 + threadIdx.x;
    f32x4 s0 = {0.f, 0.f, 0.f, 0.f};
    f32x4 s1 = {0.f, 0.f, 0.f, 0.f};
    f32x4 s2 = {0.f, 0.f, 0.f, 0.f};
    f32x4 s3 = {0.f, 0.f, 0.f, 0.f};
#pragma unroll
    for (int j = 0; j < 4; ++j) {
        s0 += mk[base + j * 256];
        s1 += km[base + j * 256];
        s2 += mv[base + j * 256];
        s3 += vm[base + j * 256];
    }
    f32x4 s = (s0 + s1) + (s2 + s3);
    probe_out[blockIdx.x * 256 + threadIdx.x] = s.x + s.y + s.z + s.w;
}

// ---------------------------------------------------------------------------
// Keys pass: outk = mk + MOMENTUM * km (3 chip-wide streams).
// Counts scatter-add fused into the first 128 blocks.
// ---------------------------------------------------------------------------
__global__ void __launch_bounds__(256) mw_keys_kernel(
        const f32x4* __restrict__ mk,
        const f32x4* __restrict__ km,
        f32x4* __restrict__ outk,
        const float* __restrict__ gate,
        const int* __restrict__ top_idx,
        float* __restrict__ counts) {
    int bid = blockIdx.x;
    int gtid = bid * 256 + threadIdx.x;

    if (gtid < B_SZ * K_TOP) {
        int a = gtid >> 3;
        float g = gate[a];
        float w = (g > GATE_THRESH) ? g * UPDATE_RATE : 0.0f;
        if (w != 0.0f) {
            atomicAdd(&counts[top_idx[gtid]], w);
        }
    }

    int base = bid * 512 + threadIdx.x;
    f32x4 a0 = mk[base];
    f32x4 a1 = mk[base + 256];
    f32x4 b0 = km[base];
    f32x4 b1 = km[base + 256];
    outk[base]       = a0 + MOMENTUM * b0;
    outk[base + 256] = a1 + MOMENTUM * b1;
}

// ---------------------------------------------------------------------------
// Values pass: outv = mv + MOMENTUM * vm (3 chip-wide streams).
// ---------------------------------------------------------------------------
__global__ void __launch_bounds__(256) mw_values_kernel(
        const f32x4* __restrict__ mv,
        const f32x4* __restrict__ vm,
        f32x4* __restrict__ outv) {
    int base = blockIdx.x * 512 + threadIdx.x;
    f32x4 a0 = mv[base];
    f32x4 a1 = mv[base + 256];
    f32x4 b0 = vm[base];
    f32x4 b1 = vm[base + 256];
    outv[base]       = a0 + MOMENTUM * b0;
    outv[base + 256] = a1 + MOMENTUM * b1;
}

// ---------------------------------------------------------------------------
// Scatter normalized updates. One block per write `a`.
// ---------------------------------------------------------------------------
__global__ void __launch_bounds__(256) mw_scatter_kernel(
        const float* __restrict__ q,
        const float* __restrict__ v,
        const float* __restrict__ gate,
        const int* __restrict__ top_idx,
        const float* __restrict__ counts,
        float* __restrict__ outk,
        float* __restrict__ outv) {
    int a = blockIdx.x;                   // 0 .. B-1
    float g = gate[a];
    float w = (g > GATE_THRESH) ? g * UPDATE_RATE : 0.0f;
    if (w == 0.0f) return;                // block-uniform exit
    int t = threadIdx.x;
    int d = t & (DIM - 1);
    bool is_key = (t < DIM);
    float x = is_key ? q[a * DIM + d] : v[a * DIM + d];
    float* base = is_key ? outk : outv;
    float wm = (1.0f - MOMENTUM) * w;
#pragma unroll
    for (int k = 0; k < K_TOP; ++k) {
        int s = top_idx[a * K_TOP + k];
        float cnt = counts[s];
        float denom = (cnt > 0.0f) ? cnt : 1.0f;
        float c = wm / denom;
        atomicAdd(&base[s * DIM + d], c * x);
    }
}

extern "C" void kernel_launch(void* const* d_in, const int* in_sizes, int n_in,
                              void* d_out, int out_size, void* d_ws, size_t ws_size,
                              hipStream_t stream) {
    const float* memory_keys    = (const float*)d_in[0];
    const float* memory_values  = (const float*)d_in[1];
    const float* write_query    = (const float*)d_in[2];
    const float* write_value    = (const float*)d_in[3];
    const float* gate_weights   = (const float*)d_in[4];
    const int*   top_indices    = (const int*)d_in[5];
    const float* key_momentum   = (const float*)d_in[6];
    const float* value_momentum = (const float*)d_in[7];

    float* out  = (float*)d_out;
    float* outk = out;
    float* outv = out + (size_t)N_SLOTS * DIM;

    float* counts    = (float*)d_ws;                        // 256 KB
    float* probe_out = (float*)((char*)d_ws + (1 << 20));   // 2 MB at +1 MB

    // 0) zero the counts accumulator
    hipMemsetAsync(counts, 0, N_SLOTS * sizeof(float), stream);

    // 1) MEASUREMENT: pure-read probe over all inputs (134 MB)
    {
        mw_read_probe<<<2048, 256, 0, stream>>>(
            (const f32x4*)memory_keys, (const f32x4*)key_momentum,
            (const f32x4*)memory_values, (const f32x4*)value_momentum,
            probe_out);
    }

    // 2) keys half (3 streams) + fused counts
    {
        int grid = N_SLOTS * DIM / 4 / 512;    // 4096 blocks
        mw_keys_kernel<<<grid, 256, 0, stream>>>(
            (const f32x4*)memory_keys, (const f32x4*)key_momentum,
            (f32x4*)outk, gate_weights, top_indices, counts);
    }

    // 3) values half (3 streams)
    {
        int grid = N_SLOTS * DIM / 4 / 512;    // 4096 blocks
        mw_values_kernel<<<grid, 256, 0, stream>>>(
            (const f32x4*)memory_values, (const f32x4*)value_momentum,
            (f32x4*)outv);
    }

    // 4) scatter normalized updates into the output
    {
        mw_scatter_kernel<<<B_SZ, 256, 0, stream>>>(
            write_query, write_value, gate_weights, top_indices, counts,
            outk, outv);
    }
}

// Round 7
// 67.201 us; speedup vs baseline: 1.2983x; 1.2983x over previous
//
#include <hip/hip_runtime.h>

#define N_SLOTS 65536
#define DIM 128
#define B_SZ 4096
#define K_TOP 8
#define UPDATE_RATE 0.1f
#define MOMENTUM 0.9f
#define GATE_THRESH 0.01f

typedef float f32x4 __attribute__((ext_vector_type(4)));

// Guaranteed-NT store: global_store_dwordx4 with the nt flag (bypass/low-
// priority allocate in L2/MALL). Dispatch-end fence makes it visible to the
// following scatter kernel.
__device__ __forceinline__ void nt_store_f32x4(f32x4* p, f32x4 v) {
    asm volatile("global_store_dwordx4 %0, %1, off nt"
                 :: "v"(p), "v"(v)
                 : "memory");
}

// ---------------------------------------------------------------------------
// Base pass (R4 structure + NT stores): out = memory + MOMENTUM * momentum.
// Blocks [0,4096) do keys, [4096,8192) values: 3 streams per wave.
// 2 f32x4 per thread, lane-contiguous. Counts scatter fused into the first
// 128 blocks; kernel-end barrier orders it before the scatter kernel.
// ---------------------------------------------------------------------------
__global__ void __launch_bounds__(256) mw_base_kernel(
        const f32x4* __restrict__ mk,
        const f32x4* __restrict__ mv,
        const f32x4* __restrict__ km,
        const f32x4* __restrict__ vm,
        f32x4* __restrict__ outk,
        f32x4* __restrict__ outv,
        const float* __restrict__ gate,
        const int* __restrict__ top_idx,
        float* __restrict__ counts) {
    int bid = blockIdx.x;
    int gtid = bid * 256 + threadIdx.x;

    // fused counts scatter (first 128 blocks only)
    if (gtid < B_SZ * K_TOP) {
        int a = gtid >> 3;
        float g = gate[a];
        float w = (g > GATE_THRESH) ? g * UPDATE_RATE : 0.0f;
        if (w != 0.0f) {
            atomicAdd(&counts[top_idx[gtid]], w);
        }
    }

    int half = bid >> 12;                 // 0 = keys, 1 = values
    int blk  = bid & 4095;

    const f32x4* __restrict__ mem = half ? mv : mk;
    const f32x4* __restrict__ mom = half ? vm : km;
    f32x4* __restrict__ out       = half ? outv : outk;

    int base = blk * 512 + threadIdx.x;
    f32x4 a0 = mem[base];
    f32x4 a1 = mem[base + 256];
    f32x4 b0 = mom[base];
    f32x4 b1 = mom[base + 256];
    f32x4 r0 = a0 + MOMENTUM * b0;
    f32x4 r1 = a1 + MOMENTUM * b1;
    nt_store_f32x4(&out[base], r0);
    nt_store_f32x4(&out[base + 256], r1);
}

// ---------------------------------------------------------------------------
// Scatter normalized updates. One block per write `a`: lanes 0..127 own the
// key row, 128..255 the value row; k-loop inside so q/v load once per block.
// ---------------------------------------------------------------------------
__global__ void __launch_bounds__(256) mw_scatter_kernel(
        const float* __restrict__ q,
        const float* __restrict__ v,
        const float* __restrict__ gate,
        const int* __restrict__ top_idx,
        const float* __restrict__ counts,
        float* __restrict__ outk,
        float* __restrict__ outv) {
    int a = blockIdx.x;                   // 0 .. B-1
    float g = gate[a];
    float w = (g > GATE_THRESH) ? g * UPDATE_RATE : 0.0f;
    if (w == 0.0f) return;                // block-uniform exit
    int t = threadIdx.x;
    int d = t & (DIM - 1);
    bool is_key = (t < DIM);
    float x = is_key ? q[a * DIM + d] : v[a * DIM + d];
    float* base = is_key ? outk : outv;
    float wm = (1.0f - MOMENTUM) * w;
#pragma unroll
    for (int k = 0; k < K_TOP; ++k) {
        int s = top_idx[a * K_TOP + k];
        float cnt = counts[s];
        float denom = (cnt > 0.0f) ? cnt : 1.0f;
        float c = wm / denom;
        atomicAdd(&base[s * DIM + d], c * x);
    }
}

extern "C" void kernel_launch(void* const* d_in, const int* in_sizes, int n_in,
                              void* d_out, int out_size, void* d_ws, size_t ws_size,
                              hipStream_t stream) {
    const float* memory_keys    = (const float*)d_in[0];
    const float* memory_values  = (const float*)d_in[1];
    const float* write_query    = (const float*)d_in[2];
    const float* write_value    = (const float*)d_in[3];
    const float* gate_weights   = (const float*)d_in[4];
    const int*   top_indices    = (const int*)d_in[5];
    const float* key_momentum   = (const float*)d_in[6];
    const float* value_momentum = (const float*)d_in[7];

    float* out  = (float*)d_out;
    float* outk = out;
    float* outv = out + (size_t)N_SLOTS * DIM;

    float* counts = (float*)d_ws;         // 65536 floats = 256 KB

    // 0) zero the counts accumulator (deterministic per call)
    hipMemsetAsync(counts, 0, N_SLOTS * sizeof(float), stream);

    // 1) fused base pass (block-halved, NT stores) + counts scatter
    {
        int grid = 8192;                  // 4096 blocks per half
        mw_base_kernel<<<grid, 256, 0, stream>>>(
            (const f32x4*)memory_keys, (const f32x4*)memory_values,
            (const f32x4*)key_momentum, (const f32x4*)value_momentum,
            (f32x4*)outk, (f32x4*)outv,
            gate_weights, top_indices, counts);
    }

    // 2) scatter normalized updates into the output
    {
        mw_scatter_kernel<<<B_SZ, 256, 0, stream>>>(
            write_query, write_value, gate_weights, top_indices, counts,
            outk, outv);
    }
}